// Round 1
// baseline (255.642 us; speedup 1.0000x reference)
//
#include <hip/hip_runtime.h>
#include <hip/hip_fp16.h>
#include <cstdint>
#include <cstddef>
#include <math.h>

#define B_ 2
#define T_ 2048
#define D_ 1024
#define M_ (B_*T_)

// column layout of P (= row layout of W concat), all offsets multiples of 8
#define QO0 0
#define KO0 128
#define WO0 160
#define QO1 168
#define KO1 680
#define WO1 744
#define QO2 752
#define KO2 2800
#define WO2 2928
#define SELO 2944
#define LDN 3072

typedef float f32x16 __attribute__((ext_vector_type(16)));
typedef short bf16x8 __attribute__((ext_vector_type(8)));
typedef unsigned short u16;

__device__ __forceinline__ u16 f2bf(float f) {
    unsigned int u = __float_as_uint(f);
    unsigned int r = (u + 0x7fffu + ((u >> 16) & 1u)) >> 16;   // RNE
    return (u16)r;
}
__device__ __forceinline__ float bf2f(u16 b) {
    return __uint_as_float(((unsigned int)b) << 16);
}

// async global->LDS, 16B per lane, dest = wave-uniform base + lane*16
__device__ __forceinline__ void gload16(const void* g, void* l) {
    __builtin_amdgcn_global_load_lds(
        (const __attribute__((address_space(1))) unsigned int*)g,
        (__attribute__((address_space(3))) unsigned int*)l,
        16, 0, 0);
}

// Bank-conflict-free 16row x 32col u16 plane-slice staging with XOR swizzle.
// LDS slot s of row r holds logical 8-u16 chunk s ^ tkey(r), tkey(r) = (r&3)^((r>>2)&3).
__device__ __forceinline__ void stage_plane(const u16* src_base, int row_stride, int k0,
                                            int rg, int lane, u16* dst) {
    int rl  = lane >> 2;
    int row = rg * 16 + rl;
    int q   = (lane & 3) ^ (rl & 3) ^ ((rl >> 2) & 3);
    const u16* s = src_base + (size_t)row * row_stride + k0 + q * 8;
    gload16(s, dst + rg * 512);
}

// ---------------- pass 1: partial sums over t (16-row chunks) + x -> bf16 ----------------
__global__ void stats1(const float* __restrict__ x, float* __restrict__ part,
                       float* __restrict__ part2, u16* __restrict__ Xh) {
    int d  = blockIdx.x * 256 + threadIdx.x;
    int tc = blockIdx.y;                       // 0..127
    int b  = blockIdx.z;
    size_t base = (size_t)b * T_ * D_ + (size_t)tc * 16 * D_ + d;
    float s = 0.f, s2 = 0.f;
#pragma unroll
    for (int t = 0; t < 16; ++t) {
        float v = x[base + (size_t)t * D_];
        s += v; s2 += v * v;
        Xh[base + (size_t)t * D_] = f2bf(v);
    }
    part [(b * 128 + tc) * D_ + d] = s;
    part2[(b * 128 + tc) * D_ + d] = s2;
}

// ---------------- pass 2: finalize mean+std, fold msd & s1 ----------------
__global__ void stats2(const float* __restrict__ part, const float* __restrict__ part2,
                       const float* __restrict__ w1,
                       float* __restrict__ msd, float* __restrict__ s1) {
    __shared__ float msL[1024];
    __shared__ float ps[64][17];
    __shared__ float pw[64][17];
    int b = blockIdx.x, tid = threadIdx.x;
    float s = 0.f, s2 = 0.f;
#pragma unroll 8
    for (int i = 0; i < 128; ++i) {
        s  += part [(b * 128 + i) * D_ + tid];
        s2 += part2[(b * 128 + i) * D_ + tid];
    }
    float mean = s / (float)T_;
    float var  = (s2 - (float)T_ * mean * mean) / (float)(T_ - 1);
    msL[tid] = mean + sqrtf(fmaxf(var, 0.f));
    __syncthreads();
    int j = tid >> 4, cc = tid & 15;
    float am = 0.f, aw = 0.f;
    const float* wr = w1 + (size_t)j * D_ + cc * 64;
    const float* mr = msL + cc * 64;
    for (int dd = 0; dd < 64; ++dd) { float w = wr[dd]; am += mr[dd] * w; aw += w; }
    ps[j][cc] = am; pw[j][cc] = aw;
    __syncthreads();
    if (tid < 64) {
        float sm = 0.f, sw = 0.f;
        for (int i = 0; i < 16; ++i) { sm += ps[tid][i]; sw += pw[tid][i]; }
        msd[b * 64 + tid] = sm;
        if (b == 0) s1[tid] = sw;
    }
}

// ---------------- weight concat -> bf16: Wh[3072][1024] ----------------
__global__ void split_w(const float* __restrict__ qw0, const float* __restrict__ kw0,
                        const float* __restrict__ ww0, const float* __restrict__ qw1,
                        const float* __restrict__ kw1, const float* __restrict__ ww1,
                        const float* __restrict__ qw2, const float* __restrict__ kw2,
                        const float* __restrict__ ww2, const float* __restrict__ w1s,
                        u16* __restrict__ Wh) {
    int row = blockIdx.x;
    int col = threadIdx.x * 4;
    const float* src = nullptr;
    if      (row < 128)  src = qw0 + (size_t)row * D_;
    else if (row < 160)  src = kw0 + (size_t)(row - 128) * D_;
    else if (row < 164)  src = ww0 + (size_t)(row - 160) * D_;
    else if (row < 168)  src = nullptr;
    else if (row < 680)  src = qw1 + (size_t)(row - 168) * D_;
    else if (row < 744)  src = kw1 + (size_t)(row - 680) * D_;
    else if (row < 752)  src = ww1 + (size_t)(row - 744) * D_;
    else if (row < 2800) src = qw2 + (size_t)(row - 752) * D_;
    else if (row < 2928) src = kw2 + (size_t)(row - 2800) * D_;
    else if (row < 2944) src = ww2 + (size_t)(row - 2928) * D_;
    else if (row < 3008) src = w1s + (size_t)(row - 2944) * D_;
    float4 v = src ? *(const float4*)(src + col) : make_float4(0.f, 0.f, 0.f, 0.f);
    ushort4 h;
    h.x = f2bf(v.x); h.y = f2bf(v.y); h.z = f2bf(v.z); h.w = f2bf(v.w);
    *(ushort4*)&Wh[(size_t)row * D_ + col] = h;
}

// ---------------- projection GEMM, m97-style: BK=64 single-buffered ----------------
__global__ __launch_bounds__(256, 3) void proj_gemm(
    const u16* __restrict__ Xh, const u16* __restrict__ Wh, u16* __restrict__ Ph) {
    __shared__ u16 As[8192], Bs[8192];   // 128 rows x 64 cols (2 planes of 32)
    int tid = threadIdx.x;
    int wave = tid >> 6, lane = tid & 63;
    int bm = blockIdx.x * 128, bn = blockIdx.y * 128;
    int wt = wave >> 1, wn = wave & 1;
    int fm = lane & 31, hv = lane >> 5;
    int tkey = (fm & 3) ^ ((fm >> 2) & 3);
    f32x16 acc[2][2];
#pragma unroll
    for (int i = 0; i < 2; ++i)
#pragma unroll
        for (int j = 0; j < 2; ++j)
#pragma unroll
            for (int r = 0; r < 16; ++r) acc[i][j][r] = 0.f;

    const u16* xh = Xh + (size_t)bm * D_;
    const u16* wh = Wh + (size_t)bn * D_;

    for (int kc = 0; kc < 16; ++kc) {
        int k0 = kc * 64;
        // 32 staging jobs: {A,B} x {2 planes} x {8 row-groups}, 8 per wave
#pragma unroll
        for (int i = 0; i < 8; ++i) {
            int j = wave * 8 + i;
            int mat = j >> 4;
            int pl  = (j >> 3) & 1;
            int rg  = j & 7;
            stage_plane(mat ? wh : xh, D_, k0 + pl * 32, rg, lane,
                        (mat ? Bs : As) + pl * 4096);
        }
        __syncthreads();
#pragma unroll
        for (int ks = 0; ks < 4; ++ks) {
            int pl = ks >> 1;
            int slot8 = (((ks & 1) * 2 + hv) ^ tkey) * 8;
            bf16x8 a_h[2], b_h[2];
#pragma unroll
            for (int t = 0; t < 2; ++t) {
                a_h[t] = *(const bf16x8*)&As[pl * 4096 + (wt * 64 + t * 32 + fm) * 32 + slot8];
                b_h[t] = *(const bf16x8*)&Bs[pl * 4096 + (wn * 64 + t * 32 + fm) * 32 + slot8];
            }
#pragma unroll
            for (int ti = 0; ti < 2; ++ti)
#pragma unroll
                for (int tj = 0; tj < 2; ++tj)
                    acc[ti][tj] = __builtin_amdgcn_mfma_f32_32x32x16_bf16(a_h[ti], b_h[tj], acc[ti][tj], 0, 0, 0);
        }
        __syncthreads();
    }
#pragma unroll
    for (int ti = 0; ti < 2; ++ti)
#pragma unroll
        for (int tj = 0; tj < 2; ++tj)
#pragma unroll
            for (int r = 0; r < 16; ++r) {
                int row = bm + wt * 64 + ti * 32 + (r & 3) + 8 * (r >> 2) + 4 * hv;
                int col = bn + wn * 64 + tj * 32 + fm;
                Ph[(size_t)row * LDN + col] = f2bf(acc[ti][tj][r]);
            }
}

// ---------------- selector layers 2-3 + softmax + WP=w*prob (f16) ----------
__global__ void selector2(const u16* __restrict__ Ph,
                          const float* __restrict__ msd, const float* __restrict__ s1,
                          const float* __restrict__ b1, const float* __restrict__ w2,
                          const float* __restrict__ b2, const float* __restrict__ w3,
                          const float* __restrict__ b3, __half* __restrict__ WP) {
    __shared__ float h1s[4][64];
    __shared__ float h2s[4][64];
    __shared__ float lg[4][3];
    int tid = threadIdx.x;
    int slot = tid >> 6, j = tid & 63;
    int bt = blockIdx.x * 4 + slot;
    int b = bt >> 11, t = bt & 2047;
    size_t pidx = (size_t)bt * LDN + SELO + j;
    float v = bf2f(Ph[pidx])
            + msd[b * 64 + j] + 0.1f * ((float)t / (float)T_) * s1[j] + b1[j];
    h1s[slot][j] = fmaxf(v, 0.f);
    __syncthreads();
    float a2 = b2[j];
#pragma unroll 8
    for (int d = 0; d < 64; ++d) a2 = fmaf(h1s[slot][d], w2[j * 64 + d], a2);
    h2s[slot][j] = fmaxf(a2, 0.f);
    __syncthreads();
    if (j < 3) {
        float a3 = b3[j];
        for (int d = 0; d < 64; ++d) a3 = fmaf(h2s[slot][d], w3[j * 64 + d], a3);
        lg[slot][j] = a3;
    }
    __syncthreads();
    if (j < 28) {
        float m = fmaxf(lg[slot][0], fmaxf(lg[slot][1], lg[slot][2]));
        float e0 = expf(lg[slot][0] - m), e1 = expf(lg[slot][1] - m), e2 = expf(lg[slot][2] - m);
        float inv = 1.f / (e0 + e1 + e2);
        int wcol = (j < 4) ? (WO0 + j) : ((j < 12) ? (WO1 + j - 4) : (WO2 + j - 12));
        float p = ((j < 4) ? e0 : ((j < 12) ? e1 : e2)) * inv;
        float w = bf2f(Ph[(size_t)bt * LDN + wcol]);
        WP[(size_t)(b * 28 + j) * T_ + t] = __float2half(w * p);
    }
}

__device__ __forceinline__ int qcol_of(int c) {
    if (c < 2)  return QO0 + c * 64;
    if (c < 10) return QO1 + (c - 2) * 64;
    return QO2 + (c - 10) * 64;
}

// ---------------- fused relu-attention score kernel ----------------
// block 128x128, 4 waves 64x64, 42 x 64-col phases, constant-folded cfg sections
__global__ __launch_bounds__(256, 2) void score_kernel(
    const u16* __restrict__ Ph, const __half* __restrict__ WP, float* __restrict__ out) {
    __shared__ u16 Qs[2][8192];    // dbuf: 2 planes x [128][32]
    __shared__ u16 Ks[4 * 4096];   // up to 4 planes x [128][32]
    __shared__ __half wpL[3584];   // [28][128]
    int tid = threadIdx.x;
    int wave = tid >> 6, lane = tid & 63;
    int wt = wave >> 1, wn = wave & 1;
    int fm = lane & 31, hv = lane >> 5;
    int tkey = (fm & 3) ^ ((fm >> 2) & 3);

    // XCD-aware swizzle: blocks sharing a Q-tile land on one XCD
    int n = blockIdx.z * 256 + blockIdx.y * 16 + blockIdx.x;
    int p = (n & 7) * 4 + (n >> 7);
    int xb = (n >> 3) & 15;
    int b = p >> 4, yb = p & 15;
    int t0 = yb * 128, s0 = xb * 128;

    const u16* Pq = Ph + (size_t)(b * T_ + t0) * LDN;
    const u16* Pk = Ph + (size_t)(b * T_ + s0) * LDN;

    auto stageQ = [&](int buf, int qcol) {
#pragma unroll
        for (int i = 0; i < 4; ++i) {
            int j = (wave << 2) + i;
            int pl = j >> 3, rg = j & 7;
            stage_plane(Pq, LDN, qcol + pl * 32, rg, lane, &Qs[buf][pl * 4096]);
        }
    };

    // prologue: K planes 0 (KO0), 1 (KO1), 2 (KO1+32) — 3 planes x 8 row-groups = 24 jobs
#pragma unroll
    for (int i = 0; i < 6; ++i) {
        int j = i * 4 + wave;                  // 0..23
        int pl = j >> 3, rg = j & 7;
        int col = (pl == 0) ? KO0 : ((pl == 1) ? KO1 : KO1 + 32);
        stage_plane(Pk, LDN, col, rg, lane, &Ks[pl * 4096]);
    }
    // wp slice: 28 rows of 128 halfs, 7 gload jobs
#pragma unroll
    for (int i = 0; i < 2; ++i) {
        int j = i * 4 + wave;
        if (j < 7) {
            const __half* src = WP + (size_t)(b * 28 + j * 4 + (lane >> 4)) * T_ + t0 + (lane & 15) * 8;
            gload16(src, (u16*)wpL + j * 512);
        }
    }
    stageQ(0, QO0);

    f32x16 outacc[2][2], dots[2][2], Z16;
#pragma unroll
    for (int r = 0; r < 16; ++r) Z16[r] = 0.f;
#pragma unroll
    for (int i = 0; i < 2; ++i)
#pragma unroll
        for (int j = 0; j < 2; ++j)
#pragma unroll
            for (int r = 0; r < 16; ++r) { outacc[i][j][r] = 0.f; dots[i][j][r] = 0.f; }

    // relu-weight epilogue for head g (dots -> outacc)
    auto epi = [&](int g) {
#pragma unroll
        for (int ti = 0; ti < 2; ++ti) {
            int rowbase = wt * 64 + ti * 32 + 4 * hv;
#pragma unroll
            for (int rq = 0; rq < 4; ++rq) {
                const __half2* wp2 = (const __half2*)&wpL[g * 128 + rowbase + rq * 8];
                float2 f01 = __half22float2(wp2[0]);
                float2 f23 = __half22float2(wp2[1]);
                float wv[4] = {f01.x, f01.y, f23.x, f23.y};
#pragma unroll
                for (int tj = 0; tj < 2; ++tj)
#pragma unroll
                    for (int r2 = 0; r2 < 4; ++r2) {
                        int r = rq * 4 + r2;
                        outacc[ti][tj][r] += fmaxf(dots[ti][tj][r], 0.f) * wv[r2];
                    }
            }
        }
    };

    // one 64-col phase: 4 ks-steps; compile-time-constant control at call sites
    auto phase64 = [&](const u16* qb, int kpA, int kpB, bool z0, bool midBreak,
                       int gMid, bool hasEnd, int gEnd) {
#pragma unroll
        for (int ks = 0; ks < 4; ++ks) {
            int kp = (ks < 2) ? kpA : kpB;
            int slot8 = (((ks & 1) * 2 + hv) ^ tkey) * 8;
            bool zero = (ks == 0 && z0) || (ks == 2 && midBreak);
            bf16x8 kf[2], qf[2];
#pragma unroll
            for (int tj = 0; tj < 2; ++tj)
                kf[tj] = *(const bf16x8*)&Ks[kp * 4096 + (wn * 64 + tj * 32 + fm) * 32 + slot8];
#pragma unroll
            for (int ti = 0; ti < 2; ++ti)
                qf[ti] = *(const bf16x8*)&qb[(ks >> 1) * 4096 + (wt * 64 + ti * 32 + fm) * 32 + slot8];
#pragma unroll
            for (int ti = 0; ti < 2; ++ti)
#pragma unroll
                for (int tj = 0; tj < 2; ++tj)
                    dots[ti][tj] = __builtin_amdgcn_mfma_f32_32x32x16_bf16(
                        qf[ti], kf[tj], zero ? Z16 : dots[ti][tj], 0, 0, 0);
            if (ks == 1 && midBreak) epi(gMid);
            if (ks == 3 && hasEnd)   epi(gEnd);
        }
    };

    // cfg0: 2 phases, K plane 0, two d=32 heads per phase
#pragma unroll
    for (int c = 0; c < 2; ++c) {
        __syncthreads();
        stageQ((c + 1) & 1, qcol_of(c + 1));
        phase64(Qs[c & 1], 0, 0, true, true, 2 * c, true, 2 * c + 1);
    }
    // cfg1: 8 phases (one d=64 head each), K planes 1,2
    for (int h = 0; h < 8; ++h) {
        int c = 2 + h;
        __syncthreads();
        stageQ((c + 1) & 1, qcol_of(c + 1));
        phase64(Qs[c & 1], 1, 2, true, false, -1, true, 4 + h);
        if (h == 7) {
            __syncthreads();   // all waves done with cfg0/cfg1 K planes
            for (int j = wave; j < 32; j += 4) {
                int pl = j >> 3, rg = j & 7;
                stage_plane(Pk, LDN, KO2 + pl * 32, rg, lane, &Ks[pl * 4096]);
            }
        }
    }
    // cfg2: 16 heads x 2 phases (d=128), K planes 0..3
    for (int h = 0; h < 16; ++h) {
        int c = 10 + 2 * h;
        __syncthreads();
        stageQ((c + 1) & 1, qcol_of(c + 1));
        phase64(Qs[c & 1], 0, 1, true, false, -1, false, -1);
        __syncthreads();
        if (c + 1 < 41) stageQ(c & 1, qcol_of(c + 2));
        phase64(Qs[(c + 1) & 1], 2, 3, false, false, -1, true, 12 + h);
    }

#pragma unroll
    for (int ti = 0; ti < 2; ++ti)
#pragma unroll
        for (int tj = 0; tj < 2; ++tj)
#pragma unroll
            for (int r = 0; r < 16; ++r) {
                int trow = wt * 64 + ti * 32 + (r & 3) + 8 * (r >> 2) + 4 * hv;
                int scol = wn * 64 + tj * 32 + fm;
                out[(size_t)(b * T_ + t0 + trow) * T_ + (s0 + scol)] = outacc[ti][tj][r];
            }
}

extern "C" void kernel_launch(void* const* d_in, const int* in_sizes, int n_in,
                              void* d_out, int out_size, void* d_ws, size_t ws_size,
                              hipStream_t stream) {
    const float* x   = (const float*)d_in[0];
    const float* w1  = (const float*)d_in[1];
    const float* b1  = (const float*)d_in[2];
    const float* w2  = (const float*)d_in[3];
    const float* b2  = (const float*)d_in[4];
    const float* w3  = (const float*)d_in[5];
    const float* b3  = (const float*)d_in[6];
    const float* qw0 = (const float*)d_in[7];
    const float* kw0 = (const float*)d_in[8];
    const float* ww0 = (const float*)d_in[9];
    const float* qw1 = (const float*)d_in[10];
    const float* kw1 = (const float*)d_in[11];
    const float* ww1 = (const float*)d_in[12];
    const float* qw2 = (const float*)d_in[13];
    const float* kw2 = (const float*)d_in[14];
    const float* ww2 = (const float*)d_in[15];
    float* out = (float*)d_out;

    float* fb = (float*)d_ws;
    float* PA  = fb; fb += (size_t)B_ * 128 * D_;   // 1 MB
    float* PA2 = fb; fb += (size_t)B_ * 128 * D_;   // 1 MB
    float* MSD = fb; fb += 128;
    float* S1  = fb; fb += 64;
    __half* WP = (__half*)fb; fb += (size_t)B_ * 28 * T_ / 2;
    u16* ub = (u16*)fb;
    u16* Wh = ub; ub += (size_t)LDN * D_;      // 6.3 MB
    u16* Xh = ub; ub += (size_t)M_ * D_;       // 8 MB
    u16* Ph = ub; ub += (size_t)M_ * LDN;      // 25 MB

    stats1<<<dim3(D_ / 256, 128, B_), 256, 0, stream>>>(x, PA, PA2, Xh);
    stats2<<<dim3(B_), 1024, 0, stream>>>(PA, PA2, w1, MSD, S1);
    split_w<<<dim3(LDN), 256, 0, stream>>>(qw0, kw0, ww0, qw1, kw1, ww1,
                                           qw2, kw2, ww2, w1, Wh);
    proj_gemm<<<dim3(M_ / 128, LDN / 128), 256, 0, stream>>>(Xh, Wh, Ph);
    selector2<<<dim3(M_ / 4), 256, 0, stream>>>(Ph, MSD, S1, b1, w2, b2, w3, b3, WP);
    score_kernel<<<dim3(T_ / 128, T_ / 128, B_), 256, 0, stream>>>(Ph, WP, out);
}

// Round 2
// 250.628 us; speedup vs baseline: 1.0200x; 1.0200x over previous
//
#include <hip/hip_runtime.h>
#include <hip/hip_fp16.h>
#include <cstdint>
#include <cstddef>
#include <math.h>

#define B_ 2
#define T_ 2048
#define D_ 1024
#define M_ (B_*T_)

// column layout of P (= row layout of W concat), all offsets multiples of 8
#define QO0 0
#define KO0 128
#define WO0 160
#define QO1 168
#define KO1 680
#define WO1 744
#define QO2 752
#define KO2 2800
#define WO2 2928
#define SELO 2944
#define LDN 3072

typedef float f32x16 __attribute__((ext_vector_type(16)));
typedef short bf16x8 __attribute__((ext_vector_type(8)));
typedef unsigned short u16;

__device__ __forceinline__ u16 f2bf(float f) {
    unsigned int u = __float_as_uint(f);
    unsigned int r = (u + 0x7fffu + ((u >> 16) & 1u)) >> 16;   // RNE
    return (u16)r;
}
__device__ __forceinline__ float bf2f(u16 b) {
    return __uint_as_float(((unsigned int)b) << 16);
}

// async global->LDS, 16B per lane, dest = wave-uniform base + lane*16
__device__ __forceinline__ void gload16(const void* g, void* l) {
    __builtin_amdgcn_global_load_lds(
        (const __attribute__((address_space(1))) unsigned int*)g,
        (__attribute__((address_space(3))) unsigned int*)l,
        16, 0, 0);
}

// Bank-conflict-free 16row x 32col u16 plane-slice staging with XOR swizzle.
// LDS slot s of row r holds logical 8-u16 chunk s ^ tkey(r), tkey(r) = (r&3)^((r>>2)&3).
__device__ __forceinline__ void stage_plane(const u16* src_base, int row_stride, int k0,
                                            int rg, int lane, u16* dst) {
    int rl  = lane >> 2;
    int row = rg * 16 + rl;
    int q   = (lane & 3) ^ (rl & 3) ^ ((rl >> 2) & 3);
    const u16* s = src_base + (size_t)row * row_stride + k0 + q * 8;
    gload16(s, dst + rg * 512);
}

// ---------------- pass 1: partial sums over t (64-row chunks) + x -> bf16 ----------------
__global__ void stats1(const float* __restrict__ x, float* __restrict__ part,
                       float* __restrict__ part2, u16* __restrict__ Xh) {
    int d  = blockIdx.x * 256 + threadIdx.x;
    int tc = blockIdx.y;                       // 0..31
    int b  = blockIdx.z;
    size_t base = (size_t)b * T_ * D_ + (size_t)tc * 64 * D_ + d;
    float s = 0.f, s2 = 0.f;
#pragma unroll 8
    for (int t = 0; t < 64; ++t) {
        float v = x[base + (size_t)t * D_];
        s += v; s2 += v * v;
        Xh[base + (size_t)t * D_] = f2bf(v);
    }
    part [(b * 32 + tc) * D_ + d] = s;
    part2[(b * 32 + tc) * D_ + d] = s2;
}

// ---------------- pass 2: finalize mean+std, fold msd & s1 ----------------
__global__ void stats2(const float* __restrict__ part, const float* __restrict__ part2,
                       const float* __restrict__ w1,
                       float* __restrict__ msd, float* __restrict__ s1) {
    __shared__ float msL[1024];
    __shared__ float ps[64][17];
    __shared__ float pw[64][17];
    int b = blockIdx.x, tid = threadIdx.x;
    float s = 0.f, s2 = 0.f;
#pragma unroll 8
    for (int i = 0; i < 32; ++i) {
        s  += part [(b * 32 + i) * D_ + tid];
        s2 += part2[(b * 32 + i) * D_ + tid];
    }
    float mean = s / (float)T_;
    float var  = (s2 - (float)T_ * mean * mean) / (float)(T_ - 1);
    msL[tid] = mean + sqrtf(fmaxf(var, 0.f));
    __syncthreads();
    int j = tid >> 4, cc = tid & 15;
    float am = 0.f, aw = 0.f;
    const float* wr = w1 + (size_t)j * D_ + cc * 64;
    const float* mr = msL + cc * 64;
    for (int dd = 0; dd < 64; ++dd) { float w = wr[dd]; am += mr[dd] * w; aw += w; }
    ps[j][cc] = am; pw[j][cc] = aw;
    __syncthreads();
    if (tid < 64) {
        float sm = 0.f, sw = 0.f;
        for (int i = 0; i < 16; ++i) { sm += ps[tid][i]; sw += pw[tid][i]; }
        msd[b * 64 + tid] = sm;
        if (b == 0) s1[tid] = sw;
    }
}

// ---------------- weight concat -> bf16: Wh[3072][1024] ----------------
__global__ void split_w(const float* __restrict__ qw0, const float* __restrict__ kw0,
                        const float* __restrict__ ww0, const float* __restrict__ qw1,
                        const float* __restrict__ kw1, const float* __restrict__ ww1,
                        const float* __restrict__ qw2, const float* __restrict__ kw2,
                        const float* __restrict__ ww2, const float* __restrict__ w1s,
                        u16* __restrict__ Wh) {
    int row = blockIdx.x;
    int col = threadIdx.x * 4;
    const float* src = nullptr;
    if      (row < 128)  src = qw0 + (size_t)row * D_;
    else if (row < 160)  src = kw0 + (size_t)(row - 128) * D_;
    else if (row < 164)  src = ww0 + (size_t)(row - 160) * D_;
    else if (row < 168)  src = nullptr;
    else if (row < 680)  src = qw1 + (size_t)(row - 168) * D_;
    else if (row < 744)  src = kw1 + (size_t)(row - 680) * D_;
    else if (row < 752)  src = ww1 + (size_t)(row - 744) * D_;
    else if (row < 2800) src = qw2 + (size_t)(row - 752) * D_;
    else if (row < 2928) src = kw2 + (size_t)(row - 2800) * D_;
    else if (row < 2944) src = ww2 + (size_t)(row - 2928) * D_;
    else if (row < 3008) src = w1s + (size_t)(row - 2944) * D_;
    float4 v = src ? *(const float4*)(src + col) : make_float4(0.f, 0.f, 0.f, 0.f);
    ushort4 h;
    h.x = f2bf(v.x); h.y = f2bf(v.y); h.z = f2bf(v.z); h.w = f2bf(v.w);
    *(ushort4*)&Wh[(size_t)row * D_ + col] = h;
}

// ---------------- projection GEMM, m97-style: BK=64 single-buffered ----------------
__global__ __launch_bounds__(256, 3) void proj_gemm(
    const u16* __restrict__ Xh, const u16* __restrict__ Wh, u16* __restrict__ Ph) {
    __shared__ u16 As[8192], Bs[8192];   // 128 rows x 64 cols (2 planes of 32)
    int tid = threadIdx.x;
    int wave = tid >> 6, lane = tid & 63;
    int bm = blockIdx.x * 128, bn = blockIdx.y * 128;
    int wt = wave >> 1, wn = wave & 1;
    int fm = lane & 31, hv = lane >> 5;
    int tkey = (fm & 3) ^ ((fm >> 2) & 3);
    f32x16 acc[2][2];
#pragma unroll
    for (int i = 0; i < 2; ++i)
#pragma unroll
        for (int j = 0; j < 2; ++j)
#pragma unroll
            for (int r = 0; r < 16; ++r) acc[i][j][r] = 0.f;

    const u16* xh = Xh + (size_t)bm * D_;
    const u16* wh = Wh + (size_t)bn * D_;

    for (int kc = 0; kc < 16; ++kc) {
        int k0 = kc * 64;
        // 32 staging jobs: {A,B} x {2 planes} x {8 row-groups}, 8 per wave
#pragma unroll
        for (int i = 0; i < 8; ++i) {
            int j = wave * 8 + i;
            int mat = j >> 4;
            int pl  = (j >> 3) & 1;
            int rg  = j & 7;
            stage_plane(mat ? wh : xh, D_, k0 + pl * 32, rg, lane,
                        (mat ? Bs : As) + pl * 4096);
        }
        __syncthreads();
#pragma unroll
        for (int ks = 0; ks < 4; ++ks) {
            int pl = ks >> 1;
            int slot8 = (((ks & 1) * 2 + hv) ^ tkey) * 8;
            bf16x8 a_h[2], b_h[2];
#pragma unroll
            for (int t = 0; t < 2; ++t) {
                a_h[t] = *(const bf16x8*)&As[pl * 4096 + (wt * 64 + t * 32 + fm) * 32 + slot8];
                b_h[t] = *(const bf16x8*)&Bs[pl * 4096 + (wn * 64 + t * 32 + fm) * 32 + slot8];
            }
#pragma unroll
            for (int ti = 0; ti < 2; ++ti)
#pragma unroll
                for (int tj = 0; tj < 2; ++tj)
                    acc[ti][tj] = __builtin_amdgcn_mfma_f32_32x32x16_bf16(a_h[ti], b_h[tj], acc[ti][tj], 0, 0, 0);
        }
        __syncthreads();
    }
#pragma unroll
    for (int ti = 0; ti < 2; ++ti)
#pragma unroll
        for (int tj = 0; tj < 2; ++tj)
#pragma unroll
            for (int r = 0; r < 16; ++r) {
                int row = bm + wt * 64 + ti * 32 + (r & 3) + 8 * (r >> 2) + 4 * hv;
                int col = bn + wn * 64 + tj * 32 + fm;
                Ph[(size_t)row * LDN + col] = f2bf(acc[ti][tj][r]);
            }
}

// ---------------- selector layers 2-3 + softmax + WP=w*prob (f16) ----------
__global__ void selector2(const u16* __restrict__ Ph,
                          const float* __restrict__ msd, const float* __restrict__ s1,
                          const float* __restrict__ b1, const float* __restrict__ w2,
                          const float* __restrict__ b2, const float* __restrict__ w3,
                          const float* __restrict__ b3, __half* __restrict__ WP) {
    __shared__ float h1s[4][64];
    __shared__ float h2s[4][64];
    __shared__ float lg[4][3];
    int tid = threadIdx.x;
    int slot = tid >> 6, j = tid & 63;
    int bt = blockIdx.x * 4 + slot;
    int b = bt >> 11, t = bt & 2047;
    size_t pidx = (size_t)bt * LDN + SELO + j;
    float v = bf2f(Ph[pidx])
            + msd[b * 64 + j] + 0.1f * ((float)t / (float)T_) * s1[j] + b1[j];
    h1s[slot][j] = fmaxf(v, 0.f);
    __syncthreads();
    float a2 = b2[j];
#pragma unroll 8
    for (int d = 0; d < 64; ++d) a2 = fmaf(h1s[slot][d], w2[j * 64 + d], a2);
    h2s[slot][j] = fmaxf(a2, 0.f);
    __syncthreads();
    if (j < 3) {
        float a3 = b3[j];
        for (int d = 0; d < 64; ++d) a3 = fmaf(h2s[slot][d], w3[j * 64 + d], a3);
        lg[slot][j] = a3;
    }
    __syncthreads();
    if (j < 28) {
        float m = fmaxf(lg[slot][0], fmaxf(lg[slot][1], lg[slot][2]));
        float e0 = expf(lg[slot][0] - m), e1 = expf(lg[slot][1] - m), e2 = expf(lg[slot][2] - m);
        float inv = 1.f / (e0 + e1 + e2);
        int wcol = (j < 4) ? (WO0 + j) : ((j < 12) ? (WO1 + j - 4) : (WO2 + j - 12));
        float p = ((j < 4) ? e0 : ((j < 12) ? e1 : e2)) * inv;
        float w = bf2f(Ph[(size_t)bt * LDN + wcol]);
        WP[(size_t)(b * 28 + j) * T_ + t] = __float2half(w * p);
    }
}

__device__ __forceinline__ int qcol_of(int c) {
    if (c < 2)  return QO0 + c * 64;
    if (c < 10) return QO1 + (c - 2) * 64;
    return QO2 + (c - 10) * 64;
}

// ---------------- fused relu-attention score kernel ----------------
// block 128x128, 4 waves 64x64. 42 x 64-col phases, two-barrier counted-vmcnt
// schedule (stage(c+1) issued pre-barrier, vmcnt(4), barrier A, compute, barrier B)
// + setprio around MFMA quads + ks-pipelined fragment loads.
__global__ __launch_bounds__(256, 2) void score_kernel(
    const u16* __restrict__ Ph, const __half* __restrict__ WP, float* __restrict__ out) {
    __shared__ u16 Qs[2][8192];    // dbuf: 2 planes x [128][32]
    __shared__ u16 Ks[4 * 4096];   // up to 4 planes x [128][32]
    __shared__ __half wpL[3584];   // [28][128]
    int tid = threadIdx.x;
    int wave = tid >> 6, lane = tid & 63;
    int wt = wave >> 1, wn = wave & 1;
    int fm = lane & 31, hv = lane >> 5;
    int tkey = (fm & 3) ^ ((fm >> 2) & 3);

    // XCD-aware swizzle: blocks sharing a Q-tile land on one XCD
    int n = blockIdx.z * 256 + blockIdx.y * 16 + blockIdx.x;
    int p = (n & 7) * 4 + (n >> 7);
    int xb = (n >> 3) & 15;
    int b = p >> 4, yb = p & 15;
    int t0 = yb * 128, s0 = xb * 128;

    const u16* Pq = Ph + (size_t)(b * T_ + t0) * LDN;
    const u16* Pk = Ph + (size_t)(b * T_ + s0) * LDN;

    auto stageQ = [&](int buf, int qcol) {
#pragma unroll
        for (int i = 0; i < 4; ++i) {
            int j = (wave << 2) + i;
            int pl = j >> 3, rg = j & 7;
            stage_plane(Pq, LDN, qcol + pl * 32, rg, lane, &Qs[buf][pl * 4096]);
        }
    };

    // prologue: K planes 0 (KO0), 1 (KO1), 2 (KO1+32) — 3 planes x 8 row-groups = 24 jobs
#pragma unroll
    for (int i = 0; i < 6; ++i) {
        int j = i * 4 + wave;                  // 0..23
        int pl = j >> 3, rg = j & 7;
        int col = (pl == 0) ? KO0 : ((pl == 1) ? KO1 : KO1 + 32);
        stage_plane(Pk, LDN, col, rg, lane, &Ks[pl * 4096]);
    }
    // wp slice: 28 rows of 128 halfs, 7 gload jobs
#pragma unroll
    for (int i = 0; i < 2; ++i) {
        int j = i * 4 + wave;
        if (j < 7) {
            const __half* src = WP + (size_t)(b * 28 + j * 4 + (lane >> 4)) * T_ + t0 + (lane & 15) * 8;
            gload16(src, (u16*)wpL + j * 512);
        }
    }
    stageQ(0, QO0);

    f32x16 outacc[2][2], dots[2][2], Z16;
#pragma unroll
    for (int r = 0; r < 16; ++r) Z16[r] = 0.f;
#pragma unroll
    for (int i = 0; i < 2; ++i)
#pragma unroll
        for (int j = 0; j < 2; ++j)
#pragma unroll
            for (int r = 0; r < 16; ++r) { outacc[i][j][r] = 0.f; dots[i][j][r] = 0.f; }

    // relu-weight epilogue for head g (dots -> outacc)
    auto epi = [&](int g) {
#pragma unroll
        for (int ti = 0; ti < 2; ++ti) {
            int rowbase = wt * 64 + ti * 32 + 4 * hv;
#pragma unroll
            for (int rq = 0; rq < 4; ++rq) {
                const __half2* wp2 = (const __half2*)&wpL[g * 128 + rowbase + rq * 8];
                float2 f01 = __half22float2(wp2[0]);
                float2 f23 = __half22float2(wp2[1]);
                float wv[4] = {f01.x, f01.y, f23.x, f23.y};
#pragma unroll
                for (int tj = 0; tj < 2; ++tj)
#pragma unroll
                    for (int r2 = 0; r2 < 4; ++r2) {
                        int r = rq * 4 + r2;
                        outacc[ti][tj][r] += fmaxf(dots[ti][tj][r], 0.f) * wv[r2];
                    }
            }
        }
    };

    // one phase: issue next stage, counted vmcnt, barrier A, ks-pipelined
    // reads+MFMA (setprio), epi, barrier B. Barrier B makes dbuf safe: no wave
    // can issue stage(c+2) (overwriting buf c&1) until all finished phase c.
    auto runPhase = [&](int c, int kpA, int kpB, bool z0, bool midBreak,
                        int gMid, bool hasEnd, int gEnd) {
        if (c + 1 < 42) {
            stageQ((c + 1) & 1, qcol_of(c + 1));
            asm volatile("s_waitcnt vmcnt(4)" ::: "memory");
        } else {
            asm volatile("s_waitcnt vmcnt(0)" ::: "memory");
        }
        __builtin_amdgcn_s_barrier();            // A: stage(c) visible to all waves
        __builtin_amdgcn_sched_barrier(0);       // no LDS reads may float above A
        const u16* qb = Qs[c & 1];

        bf16x8 kf[2][2], qf[2][2];
        auto loadks = [&](int ks, int sl) {
            int kp = (ks < 2) ? kpA : kpB;
            int slot8 = (((ks & 1) * 2 + hv) ^ tkey) * 8;
#pragma unroll
            for (int tj = 0; tj < 2; ++tj)
                kf[sl][tj] = *(const bf16x8*)&Ks[kp * 4096 + (wn * 64 + tj * 32 + fm) * 32 + slot8];
#pragma unroll
            for (int ti = 0; ti < 2; ++ti)
                qf[sl][ti] = *(const bf16x8*)&qb[(ks >> 1) * 4096 + (wt * 64 + ti * 32 + fm) * 32 + slot8];
        };
        loadks(0, 0);
#pragma unroll
        for (int ks = 0; ks < 4; ++ks) {
            if (ks < 3) loadks(ks + 1, (ks + 1) & 1);
            bool zero = (ks == 0 && z0) || (ks == 2 && midBreak);
            int sl = ks & 1;
            __builtin_amdgcn_s_setprio(1);
#pragma unroll
            for (int ti = 0; ti < 2; ++ti)
#pragma unroll
                for (int tj = 0; tj < 2; ++tj)
                    dots[ti][tj] = __builtin_amdgcn_mfma_f32_32x32x16_bf16(
                        qf[sl][ti], kf[sl][tj], zero ? Z16 : dots[ti][tj], 0, 0, 0);
            __builtin_amdgcn_s_setprio(0);
            if (ks == 1 && midBreak) epi(gMid);
            if (ks == 3 && hasEnd)   epi(gEnd);
        }
        __builtin_amdgcn_sched_barrier(0);       // all reads retired before B
        __builtin_amdgcn_s_barrier();            // B: phase-c reads done everywhere
    };

    // cfg0: 2 phases, K plane 0, two d=32 heads per phase
#pragma unroll
    for (int c = 0; c < 2; ++c)
        runPhase(c, 0, 0, true, true, 2 * c, true, 2 * c + 1);
    // cfg1: 8 phases (one d=64 head each), K planes 1,2
    for (int h = 0; h < 8; ++h) {
        runPhase(2 + h, 1, 2, true, false, -1, true, 4 + h);
        if (h == 7) {
            // after barrier B of phase 9: all waves done with cfg0/cfg1 K planes.
            // Issue KO2 restage; phase 10's vmcnt(4) (4 newest = its own stageQ)
            // guarantees these 8 loads have landed before its barrier A.
            for (int j = wave; j < 32; j += 4) {
                int pl = j >> 3, rg = j & 7;
                stage_plane(Pk, LDN, KO2 + pl * 32, rg, lane, &Ks[pl * 4096]);
            }
        }
    }
    // cfg2: 16 heads x 2 phases (d=128), K planes 0..3
    for (int h = 0; h < 16; ++h) {
        runPhase(10 + 2 * h, 0, 1, true, false, -1, false, -1);
        runPhase(11 + 2 * h, 2, 3, false, false, -1, true, 12 + h);
    }

#pragma unroll
    for (int ti = 0; ti < 2; ++ti)
#pragma unroll
        for (int tj = 0; tj < 2; ++tj)
#pragma unroll
            for (int r = 0; r < 16; ++r) {
                int trow = wt * 64 + ti * 32 + (r & 3) + 8 * (r >> 2) + 4 * hv;
                int scol = wn * 64 + tj * 32 + fm;
                out[(size_t)(b * T_ + t0 + trow) * T_ + (s0 + scol)] = outacc[ti][tj][r];
            }
}

extern "C" void kernel_launch(void* const* d_in, const int* in_sizes, int n_in,
                              void* d_out, int out_size, void* d_ws, size_t ws_size,
                              hipStream_t stream) {
    const float* x   = (const float*)d_in[0];
    const float* w1  = (const float*)d_in[1];
    const float* b1  = (const float*)d_in[2];
    const float* w2  = (const float*)d_in[3];
    const float* b2  = (const float*)d_in[4];
    const float* w3  = (const float*)d_in[5];
    const float* b3  = (const float*)d_in[6];
    const float* qw0 = (const float*)d_in[7];
    const float* kw0 = (const float*)d_in[8];
    const float* ww0 = (const float*)d_in[9];
    const float* qw1 = (const float*)d_in[10];
    const float* kw1 = (const float*)d_in[11];
    const float* ww1 = (const float*)d_in[12];
    const float* qw2 = (const float*)d_in[13];
    const float* kw2 = (const float*)d_in[14];
    const float* ww2 = (const float*)d_in[15];
    float* out = (float*)d_out;

    float* fb = (float*)d_ws;
    float* PA  = fb; fb += (size_t)B_ * 32 * D_;
    float* PA2 = fb; fb += (size_t)B_ * 32 * D_;
    float* MSD = fb; fb += 128;
    float* S1  = fb; fb += 64;
    __half* WP = (__half*)fb; fb += (size_t)B_ * 28 * T_ / 2;
    u16* ub = (u16*)fb;
    u16* Wh = ub; ub += (size_t)LDN * D_;      // 6.3 MB
    u16* Xh = ub; ub += (size_t)M_ * D_;       // 8 MB
    u16* Ph = ub; ub += (size_t)M_ * LDN;      // 25 MB

    stats1<<<dim3(D_ / 256, 32, B_), 256, 0, stream>>>(x, PA, PA2, Xh);
    stats2<<<dim3(B_), 1024, 0, stream>>>(PA, PA2, w1, MSD, S1);
    split_w<<<dim3(LDN), 256, 0, stream>>>(qw0, kw0, ww0, qw1, kw1, ww1,
                                           qw2, kw2, ww2, w1, Wh);
    proj_gemm<<<dim3(M_ / 128, LDN / 128), 256, 0, stream>>>(Xh, Wh, Ph);
    selector2<<<dim3(M_ / 4), 256, 0, stream>>>(Ph, MSD, S1, b1, w2, b2, w3, b3, WP);
    score_kernel<<<dim3(T_ / 128, T_ / 128, B_), 256, 0, stream>>>(Ph, WP, out);
}